// Round 1
// baseline (568.499 us; speedup 1.0000x reference)
//
#include <hip/hip_runtime.h>

// out = x * exp(-sigma^2/2 + sigma*eps), sigma = 0.5
// N = 8*4096*2048 = 67108864 fp32 elements; memory-bound (805 MB traffic).

#define SIGMA  0.5f
#define BIAS  (-0.125f)   // -sigma^2/2

__global__ __launch_bounds__(256) void sdo_kernel(const float4* __restrict__ x,
                                                  const float4* __restrict__ eps,
                                                  float4* __restrict__ out,
                                                  int n4) {
    int i = blockIdx.x * blockDim.x + threadIdx.x;
    if (i >= n4) return;
    float4 xv = x[i];
    float4 ev = eps[i];
    float4 ov;
    ov.x = xv.x * __expf(fmaf(SIGMA, ev.x, BIAS));
    ov.y = xv.y * __expf(fmaf(SIGMA, ev.y, BIAS));
    ov.z = xv.z * __expf(fmaf(SIGMA, ev.z, BIAS));
    ov.w = xv.w * __expf(fmaf(SIGMA, ev.w, BIAS));
    out[i] = ov;
}

extern "C" void kernel_launch(void* const* d_in, const int* in_sizes, int n_in,
                              void* d_out, int out_size, void* d_ws, size_t ws_size,
                              hipStream_t stream) {
    const float4* x   = (const float4*)d_in[0];
    const float4* eps = (const float4*)d_in[1];
    float4* out       = (float4*)d_out;
    int n  = in_sizes[0];        // 67108864
    int n4 = n >> 2;             // 16777216, exact (n % 4 == 0)
    int block = 256;
    int grid  = (n4 + block - 1) / block;  // 65536
    sdo_kernel<<<grid, block, 0, stream>>>(x, eps, out, n4);
}